// Round 4
// baseline (928.791 us; speedup 1.0000x reference)
//
#include <hip/hip_runtime.h>
#include <hip/hip_fp16.h>

// Swin-V2 window attention, fully fused, MI355X (gfx950).
// Round 4: 1 barrier/head (parity-double-buffered kh/vT/krs), per-head fused
// proj into f32x4 register accumulators (O_h transposed through the idle kh
// parity buffer), i-major bias+mask table (f16x4 loads), LDS 29440 B.

#define NTOK 49
#define DIM 192
#define NH 6
#define BATCH 4096

typedef __attribute__((ext_vector_type(4))) float f32x4;
typedef __attribute__((ext_vector_type(8))) _Float16 f16x8;
typedef __attribute__((ext_vector_type(4))) _Float16 f16x4h;

// ws layout (bytes)
#define W1_OFF 0                        // [576][192] f16
#define W2_OFF 221184                   // [192][192] f16
#define BMI_OFF 294912                  // [64*6][49(i) x 52] f16 (+slack)
#define HSC_OFF 2260992                 // [6] f32 head scales

#define MFMA16(a, b, c) __builtin_amdgcn_mfma_f32_16x16x32_f16(a, b, c, 0, 0, 0)

__global__ __launch_bounds__(256) void k_setup(
    const float* __restrict__ qkv_w, const float* __restrict__ proj_w,
    const float* __restrict__ mask, const float* __restrict__ table,
    const int* __restrict__ rel_index, const float* __restrict__ ls,
    _Float16* __restrict__ W1, _Float16* __restrict__ W2,
    _Float16* __restrict__ bmi, float* __restrict__ hsc) {
  int idx = blockIdx.x * 256 + threadIdx.x;
  if (idx < 576 * 192) W1[idx] = (_Float16)qkv_w[idx];
  if (idx < 192 * 192) W2[idx] = (_Float16)proj_w[idx];
  if (idx < NH) hsc[idx] = __expf(fminf(ls[idx], 4.60517019f));
  if (idx < 64 * NH * 2401) {
    int p = idx / 2401, rem = idx % 2401;
    int i = rem / 49, j = rem % 49;     // stored [p][i (stride 52)][j]
    int wdx = p / NH, h = p % NH;
    bmi[(size_t)p * 2548 + i * 52 + j] =
        (_Float16)(table[rel_index[i * 49 + j] * NH + h] +
                   mask[wdx * 2401 + i * 49 + j]);
  }
}

__global__ __launch_bounds__(256, 4) void k_fused(
    const float* __restrict__ x, const _Float16* __restrict__ W1,
    const float* __restrict__ qkv_b, const _Float16* __restrict__ bmi,
    const float* __restrict__ hsc, const _Float16* __restrict__ W2,
    const float* __restrict__ proj_b, float* __restrict__ out) {
  __shared__ __align__(16) char smem[29440];
  _Float16* qh = (_Float16*)smem;            // [64][72] f16, aliased by Pl
  _Float16* kh = (_Float16*)(smem + 9216);   // [2][64][40] f16 (idle buf = O_h scratch)
  _Float16* vT = (_Float16*)(smem + 19456);  // [2][32][72] f16 (v transposed)
  float* qrs = (float*)(smem + 28672);       // [64]    rsqrt(|q|^2)*scale
  float* krs = (float*)(smem + 28928);       // [2][64] rsqrt(|k|^2)

  const int b = blockIdx.x;
  const int tid = threadIdx.x;
  const int lane = tid & 63;
  const int w = tid >> 6;  // wave id = M row-tile
  const int L = lane & 15;
  const int g = lane >> 4;
  const int row0 = 16 * w + 4 * g;

  // ---- x A-fragments: rows 16w+L (zero past 49), k = 32kf + 8g .. +8 ----
  f16x8 ax[6];
  {
    const int row = 16 * w + L;
    const float* xr = x + ((size_t)b * NTOK + (row < NTOK ? row : 0)) * DIM + 8 * g;
    const f32x4 vz = {0.f, 0.f, 0.f, 0.f};
#pragma unroll
    for (int kf = 0; kf < 6; ++kf) {
      f32x4 lo = *(const f32x4*)(xr + 32 * kf);
      f32x4 hi = *(const f32x4*)(xr + 32 * kf + 4);
      if (row >= NTOK) { lo = vz; hi = vz; }
      f16x8 v;
      v[0] = (_Float16)lo[0]; v[1] = (_Float16)lo[1];
      v[2] = (_Float16)lo[2]; v[3] = (_Float16)lo[3];
      v[4] = (_Float16)hi[0]; v[5] = (_Float16)hi[1];
      v[6] = (_Float16)hi[2]; v[7] = (_Float16)hi[3];
      ax[kf] = v;
    }
  }

  f32x4 acc_out[12];
#pragma unroll
  for (int ct = 0; ct < 12; ++ct) acc_out[ct] = (f32x4){0.f, 0.f, 0.f, 0.f};

  const _Float16* bmi_b =
      bmi + (size_t)(b & 63) * NH * 2548 + (16 * w + L) * 52;

#pragma unroll 1
  for (int h = 0; h < NH; ++h) {
    const int ph = h & 1;
    _Float16* khp = kh + ph * 2560;        // this head's K
    _Float16* vTp = vT + ph * 2304;        // this head's V^T
    _Float16* ob = kh + (ph ^ 1) * 2560;   // idle parity buf = O_h scratch
    float* krp = krs + ph * 64;

    // prefetch bias+mask rows (consumed post-barrier; hides under QKV)
    f16x4h bm4[4];
    {
      const _Float16* bp = bmi_b + (size_t)h * 2548 + 4 * g;
#pragma unroll
      for (int t = 0; t < 4; ++t) bm4[t] = *(const f16x4h*)(bp + 16 * t);
    }
    const float hs = hsc[h];

    // ---- per-head QKV GEMM: q->qh, k->khp, v->vTp (transposed) ----
    float ssq[4] = {0.f, 0.f, 0.f, 0.f}, ssk[4] = {0.f, 0.f, 0.f, 0.f};
#pragma unroll
    for (int s = 0; s < 3; ++s) {
      const int col0 = s * DIM + 32 * h + L;
      const _Float16* wp0 = W1 + (size_t)col0 * DIM + 8 * g;
      f16x8 wf0[6], wf1[6];
#pragma unroll
      for (int kf = 0; kf < 6; ++kf) {
        wf0[kf] = *(const f16x8*)(wp0 + 32 * kf);
        wf1[kf] = *(const f16x8*)(wp0 + 16 * DIM + 32 * kf);
      }
      f32x4 a0 = {0.f, 0.f, 0.f, 0.f}, a1 = {0.f, 0.f, 0.f, 0.f};
#pragma unroll
      for (int kf = 0; kf < 6; ++kf) {
        a0 = MFMA16(ax[kf], wf0[kf], a0);
        a1 = MFMA16(ax[kf], wf1[kf], a1);
      }
      const float b0 = qkv_b[col0], b1 = qkv_b[col0 + 16];
      if (s == 0) {
#pragma unroll
        for (int r = 0; r < 4; ++r) {
          float v0 = a0[r] + b0, v1 = a1[r] + b1;
          qh[(row0 + r) * 72 + L] = (_Float16)v0;
          qh[(row0 + r) * 72 + 16 + L] = (_Float16)v1;
          ssq[r] += v0 * v0 + v1 * v1;
        }
      } else if (s == 1) {
#pragma unroll
        for (int r = 0; r < 4; ++r) {
          float v0 = a0[r] + b0, v1 = a1[r] + b1;
          khp[(row0 + r) * 40 + L] = (_Float16)v0;
          khp[(row0 + r) * 40 + 16 + L] = (_Float16)v1;
          ssk[r] += v0 * v0 + v1 * v1;
        }
      } else {
        f16x4h p0, p1;
#pragma unroll
        for (int r = 0; r < 4; ++r) {
          p0[r] = (_Float16)(a0[r] + b0);
          p1[r] = (_Float16)(a1[r] + b1);
        }
        *(f16x4h*)(vTp + L * 72 + row0) = p0;         // vT[d=L][n=row0..+3]
        *(f16x4h*)(vTp + (16 + L) * 72 + row0) = p1;  // vT[d=16+L][...]
      }
    }
#pragma unroll
    for (int r = 0; r < 4; ++r) {
      float sq = ssq[r], sk = ssk[r];
      sq += __shfl_xor(sq, 1); sq += __shfl_xor(sq, 2);
      sq += __shfl_xor(sq, 4); sq += __shfl_xor(sq, 8);
      sk += __shfl_xor(sk, 1); sk += __shfl_xor(sk, 2);
      sk += __shfl_xor(sk, 4); sk += __shfl_xor(sk, 8);
      if (L == 0) {
        qrs[row0 + r] = rsqrtf(fmaxf(sq, 1e-24f)) * hs;
        krp[row0 + r] = rsqrtf(fmaxf(sk, 1e-24f));
      }
    }
    __syncthreads();  // the ONLY barrier per head

    // ---- S^T = K·Q : thread holds S[i=16w+L][j=16t+4g+r] ----
    f16x8 bq = *(const f16x8*)(qh + (16 * w + L) * 72 + 8 * g);
    f32x4 st[4];
#pragma unroll
    for (int t = 0; t < 4; ++t) {
      f16x8 ak = *(const f16x8*)(khp + (16 * t + L) * 40 + 8 * g);
      f32x4 z = {0.f, 0.f, 0.f, 0.f};
      st[t] = MFMA16(ak, bq, z);
    }
    const float qr = qrs[16 * w + L];

    // ---- softmax over j, fully in-register ----
    float p[4][4];
#pragma unroll
    for (int t = 0; t < 4; ++t) {
      f32x4 kv = *(const f32x4*)(krp + 16 * t + 4 * g);
#pragma unroll
      for (int r = 0; r < 4; ++r) {
        int j = 16 * t + 4 * g + r;
        p[t][r] = (j < NTOK) ? fmaf(st[t][r], qr * kv[r], (float)bm4[t][r])
                             : -1e30f;
      }
    }
    float mx = p[0][0];
#pragma unroll
    for (int t = 0; t < 4; ++t)
#pragma unroll
      for (int r = 0; r < 4; ++r) mx = fmaxf(mx, p[t][r]);
    mx = fmaxf(mx, __shfl_xor(mx, 16));
    mx = fmaxf(mx, __shfl_xor(mx, 32));
    float sum = 0.f;
#pragma unroll
    for (int t = 0; t < 4; ++t)
#pragma unroll
      for (int r = 0; r < 4; ++r) {
        p[t][r] = __expf(p[t][r] - mx);
        sum += p[t][r];
      }
    sum += __shfl_xor(sum, 16);
    sum += __shfl_xor(sum, 32);
    const float is = 1.0f / sum;

    // ---- write normalized P into Pl (aliases qh; own rows, after bq read) ----
#pragma unroll
    for (int t = 0; t < 4; ++t) {
      f16x4h pk;
#pragma unroll
      for (int r = 0; r < 4; ++r) pk[r] = (_Float16)(p[t][r] * is);
      *(f16x4h*)(qh + (16 * w + L) * 72 + 16 * t + 4 * g) = pk;
    }

    // ---- PV: O[i][d] = sum_j P[i][j] vT[d][j] (same-wave LDS RAW) ----
    f16x8 pa0 = *(const f16x8*)(qh + (16 * w + L) * 72 + 8 * g);
    f16x8 pa1 = *(const f16x8*)(qh + (16 * w + L) * 72 + 32 + 8 * g);
#pragma unroll
    for (int dt = 0; dt < 2; ++dt) {
      f16x8 bv0 = *(const f16x8*)(vTp + (16 * dt + L) * 72 + 8 * g);
      f16x8 bv1 = *(const f16x8*)(vTp + (16 * dt + L) * 72 + 32 + 8 * g);
      f32x4 o4 = {0.f, 0.f, 0.f, 0.f};
      o4 = MFMA16(pa0, bv0, o4);
      o4 = MFMA16(pa1, bv1, o4);
#pragma unroll
      for (int r = 0; r < 4; ++r)
        ob[(row0 + r) * 40 + 16 * dt + L] = (_Float16)o4[r];
    }

    // ---- proj partial: acc_out += O_h @ W2[:,32h:32h+32]^T ----
    f16x8 aa = *(const f16x8*)(ob + (16 * w + L) * 40 + 8 * g);
#pragma unroll
    for (int ct = 0; ct < 12; ++ct) {
      f16x8 w2f = *(const f16x8*)(W2 + (size_t)(16 * ct + L) * DIM + 32 * h + 8 * g);
      acc_out[ct] = MFMA16(aa, w2f, acc_out[ct]);
    }
  }

  // ---- epilogue: out = acc_out + proj_b ----
#pragma unroll
  for (int ct = 0; ct < 12; ++ct) {
    const float pb_ = proj_b[16 * ct + L];
#pragma unroll
    for (int r = 0; r < 4; ++r) {
      int row = row0 + r;
      if (row < NTOK)
        out[((size_t)b * NTOK + row) * DIM + 16 * ct + L] = acc_out[ct][r] + pb_;
    }
  }
}

extern "C" void kernel_launch(void* const* d_in, const int* in_sizes, int n_in,
                              void* d_out, int out_size, void* d_ws, size_t ws_size,
                              hipStream_t stream) {
  const float* x     = (const float*)d_in[0];
  const float* mask  = (const float*)d_in[1];
  const float* qkv_w = (const float*)d_in[2];
  const float* qkv_b = (const float*)d_in[3];
  const float* ls    = (const float*)d_in[4];
  const float* tbl   = (const float*)d_in[5];
  const int*   ridx  = (const int*)d_in[6];
  const float* pw    = (const float*)d_in[7];
  const float* pb    = (const float*)d_in[8];
  float* out = (float*)d_out;
  char* ws = (char*)d_ws;

  _Float16* W1 = (_Float16*)(ws + W1_OFF);
  _Float16* W2 = (_Float16*)(ws + W2_OFF);
  _Float16* bmi = (_Float16*)(ws + BMI_OFF);
  float* hsc = (float*)(ws + HSC_OFF);

  hipLaunchKernelGGL(k_setup, dim3(3602), dim3(256), 0, stream,
                     qkv_w, pw, mask, tbl, ridx, ls, W1, W2, bmi, hsc);
  hipLaunchKernelGGL(k_fused, dim3(BATCH), dim3(256), 0, stream,
                     x, W1, qkv_b, bmi, hsc, W2, pb, out);
}

// Round 5
// 700.658 us; speedup vs baseline: 1.3256x; 1.3256x over previous
//
#include <hip/hip_runtime.h>
#include <hip/hip_fp16.h>

// Swin-V2 window attention, fully fused, MI355X (gfx950).
// Round 5: round-4 structure (1 barrier/head, parity-buffered kh/vT/krs,
// per-head proj into f32x4 register accumulators) with register pressure
// fixed: sequential col-tiles in QKV (one wf[6] buffer), bias+mask prefetch
// moved post-barrier. Target: no scratch spill (round 4 spilled acc_out ->
// +2.4 GB HBM traffic).

#define NTOK 49
#define DIM 192
#define NH 6
#define BATCH 4096

typedef __attribute__((ext_vector_type(4))) float f32x4;
typedef __attribute__((ext_vector_type(8))) _Float16 f16x8;
typedef __attribute__((ext_vector_type(4))) _Float16 f16x4h;

// ws layout (bytes)
#define W1_OFF 0                        // [576][192] f16
#define W2_OFF 221184                   // [192][192] f16
#define BMI_OFF 294912                  // [64*6][49(i) x 52] f16 (+slack)
#define HSC_OFF 2260992                 // [6] f32 head scales

#define MFMA16(a, b, c) __builtin_amdgcn_mfma_f32_16x16x32_f16(a, b, c, 0, 0, 0)

__global__ __launch_bounds__(256) void k_setup(
    const float* __restrict__ qkv_w, const float* __restrict__ proj_w,
    const float* __restrict__ mask, const float* __restrict__ table,
    const int* __restrict__ rel_index, const float* __restrict__ ls,
    _Float16* __restrict__ W1, _Float16* __restrict__ W2,
    _Float16* __restrict__ bmi, float* __restrict__ hsc) {
  int idx = blockIdx.x * 256 + threadIdx.x;
  if (idx < 576 * 192) W1[idx] = (_Float16)qkv_w[idx];
  if (idx < 192 * 192) W2[idx] = (_Float16)proj_w[idx];
  if (idx < NH) hsc[idx] = __expf(fminf(ls[idx], 4.60517019f));
  if (idx < 64 * NH * 2401) {
    int p = idx / 2401, rem = idx % 2401;
    int i = rem / 49, j = rem % 49;     // stored [p][i (stride 52)][j]
    int wdx = p / NH, h = p % NH;
    bmi[(size_t)p * 2548 + i * 52 + j] =
        (_Float16)(table[rel_index[i * 49 + j] * NH + h] +
                   mask[wdx * 2401 + i * 49 + j]);
  }
}

__global__ __launch_bounds__(256, 4) void k_fused(
    const float* __restrict__ x, const _Float16* __restrict__ W1,
    const float* __restrict__ qkv_b, const _Float16* __restrict__ bmi,
    const float* __restrict__ hsc, const _Float16* __restrict__ W2,
    const float* __restrict__ proj_b, float* __restrict__ out) {
  __shared__ __align__(16) char smem[29440];
  _Float16* qh = (_Float16*)smem;            // [64][72] f16 (Q cols 0..32; P alias)
  _Float16* kh = (_Float16*)(smem + 9216);   // [2][64][40] f16 (idle buf = O_h scratch)
  _Float16* vT = (_Float16*)(smem + 19456);  // [2][32][72] f16 (v transposed)
  float* qrs = (float*)(smem + 28672);       // [64]    rsqrt(|q|^2)*scale
  float* krs = (float*)(smem + 28928);       // [2][64] rsqrt(|k|^2)

  const int b = blockIdx.x;
  const int tid = threadIdx.x;
  const int lane = tid & 63;
  const int w = tid >> 6;  // wave id = M row-tile
  const int L = lane & 15;
  const int g = lane >> 4;
  const int row0 = 16 * w + 4 * g;

  // ---- x A-fragments: rows 16w+L (zero past 49), k = 32kf + 8g .. +8 ----
  f16x8 ax[6];
  {
    const int row = 16 * w + L;
    const float* xr = x + ((size_t)b * NTOK + (row < NTOK ? row : 0)) * DIM + 8 * g;
    const f32x4 vz = {0.f, 0.f, 0.f, 0.f};
#pragma unroll
    for (int kf = 0; kf < 6; ++kf) {
      f32x4 lo = *(const f32x4*)(xr + 32 * kf);
      f32x4 hi = *(const f32x4*)(xr + 32 * kf + 4);
      if (row >= NTOK) { lo = vz; hi = vz; }
      f16x8 v;
      v[0] = (_Float16)lo[0]; v[1] = (_Float16)lo[1];
      v[2] = (_Float16)lo[2]; v[3] = (_Float16)lo[3];
      v[4] = (_Float16)hi[0]; v[5] = (_Float16)hi[1];
      v[6] = (_Float16)hi[2]; v[7] = (_Float16)hi[3];
      ax[kf] = v;
    }
  }

  f32x4 acc_out[12];
#pragma unroll
  for (int ct = 0; ct < 12; ++ct) acc_out[ct] = (f32x4){0.f, 0.f, 0.f, 0.f};

  const _Float16* bmi_b =
      bmi + (size_t)(b & 63) * NH * 2548 + (16 * w + L) * 52;

#pragma unroll 1
  for (int h = 0; h < NH; ++h) {
    const int ph = h & 1;
    _Float16* khp = kh + ph * 2560;        // this head's K
    _Float16* vTp = vT + ph * 2304;        // this head's V^T
    _Float16* ob = kh + (ph ^ 1) * 2560;   // idle parity buf = O_h scratch
    float* krp = krs + ph * 64;
    const float hs = hsc[h];

    // ---- per-head QKV GEMM: q->qh, k->khp, v->vTp (transposed) ----
    float ssq[4] = {0.f, 0.f, 0.f, 0.f}, ssk[4] = {0.f, 0.f, 0.f, 0.f};
#pragma unroll
    for (int s = 0; s < 3; ++s) {
#pragma unroll
      for (int ct = 0; ct < 2; ++ct) {
        const int col = s * DIM + 32 * h + 16 * ct + L;
        const _Float16* wp = W1 + (size_t)col * DIM + 8 * g;
        f32x4 acc = {0.f, 0.f, 0.f, 0.f};
#pragma unroll
        for (int kf = 0; kf < 6; ++kf)
          acc = MFMA16(ax[kf], *(const f16x8*)(wp + 32 * kf), acc);
        const float bias = qkv_b[col];
        if (s == 0) {
#pragma unroll
          for (int r = 0; r < 4; ++r) {
            float v = acc[r] + bias;
            qh[(row0 + r) * 72 + 16 * ct + L] = (_Float16)v;
            ssq[r] += v * v;
          }
        } else if (s == 1) {
#pragma unroll
          for (int r = 0; r < 4; ++r) {
            float v = acc[r] + bias;
            khp[(row0 + r) * 40 + 16 * ct + L] = (_Float16)v;
            ssk[r] += v * v;
          }
        } else {
          f16x4h pk;
#pragma unroll
          for (int r = 0; r < 4; ++r) pk[r] = (_Float16)(acc[r] + bias);
          *(f16x4h*)(vTp + (16 * ct + L) * 72 + row0) = pk;
        }
      }
    }
#pragma unroll
    for (int r = 0; r < 4; ++r) {
      float sq = ssq[r], sk = ssk[r];
      sq += __shfl_xor(sq, 1); sq += __shfl_xor(sq, 2);
      sq += __shfl_xor(sq, 4); sq += __shfl_xor(sq, 8);
      sk += __shfl_xor(sk, 1); sk += __shfl_xor(sk, 2);
      sk += __shfl_xor(sk, 4); sk += __shfl_xor(sk, 8);
      if (L == 0) {
        qrs[row0 + r] = rsqrtf(fmaxf(sq, 1e-24f)) * hs;
        krp[row0 + r] = rsqrtf(fmaxf(sk, 1e-24f));
      }
    }
    __syncthreads();  // the ONLY barrier per head

    // prefetch bias+mask rows (global/L2; consumed in softmax below)
    f16x4h bm4[4];
    {
      const _Float16* bp = bmi_b + (size_t)h * 2548 + 4 * g;
#pragma unroll
      for (int t = 0; t < 4; ++t) bm4[t] = *(const f16x4h*)(bp + 16 * t);
    }

    // ---- S^T = K·Q : thread holds S[i=16w+L][j=16t+4g+r] ----
    f16x8 bq = *(const f16x8*)(qh + (16 * w + L) * 72 + 8 * g);
    f32x4 st[4];
#pragma unroll
    for (int t = 0; t < 4; ++t) {
      f16x8 ak = *(const f16x8*)(khp + (16 * t + L) * 40 + 8 * g);
      f32x4 z = {0.f, 0.f, 0.f, 0.f};
      st[t] = MFMA16(ak, bq, z);
    }
    const float qr = qrs[16 * w + L];

    // ---- softmax over j, fully in-register ----
    float p[4][4];
#pragma unroll
    for (int t = 0; t < 4; ++t) {
      f32x4 kv = *(const f32x4*)(krp + 16 * t + 4 * g);
#pragma unroll
      for (int r = 0; r < 4; ++r) {
        int j = 16 * t + 4 * g + r;
        p[t][r] = (j < NTOK) ? fmaf(st[t][r], qr * kv[r], (float)bm4[t][r])
                             : -1e30f;
      }
    }
    float mx = p[0][0];
#pragma unroll
    for (int t = 0; t < 4; ++t)
#pragma unroll
      for (int r = 0; r < 4; ++r) mx = fmaxf(mx, p[t][r]);
    mx = fmaxf(mx, __shfl_xor(mx, 16));
    mx = fmaxf(mx, __shfl_xor(mx, 32));
    float sum = 0.f;
#pragma unroll
    for (int t = 0; t < 4; ++t)
#pragma unroll
      for (int r = 0; r < 4; ++r) {
        p[t][r] = __expf(p[t][r] - mx);
        sum += p[t][r];
      }
    sum += __shfl_xor(sum, 16);
    sum += __shfl_xor(sum, 32);
    const float is = 1.0f / sum;

    // ---- write normalized P into qh alias (own rows, after bq read) ----
#pragma unroll
    for (int t = 0; t < 4; ++t) {
      f16x4h pk;
#pragma unroll
      for (int r = 0; r < 4; ++r) pk[r] = (_Float16)(p[t][r] * is);
      *(f16x4h*)(qh + (16 * w + L) * 72 + 16 * t + 4 * g) = pk;
    }

    // ---- PV: O[i][d] = sum_j P[i][j] vT[d][j] (same-wave LDS RAW) ----
    f16x8 pa0 = *(const f16x8*)(qh + (16 * w + L) * 72 + 8 * g);
    f16x8 pa1 = *(const f16x8*)(qh + (16 * w + L) * 72 + 32 + 8 * g);
#pragma unroll
    for (int dt = 0; dt < 2; ++dt) {
      f16x8 bv0 = *(const f16x8*)(vTp + (16 * dt + L) * 72 + 8 * g);
      f16x8 bv1 = *(const f16x8*)(vTp + (16 * dt + L) * 72 + 32 + 8 * g);
      f32x4 o4 = {0.f, 0.f, 0.f, 0.f};
      o4 = MFMA16(pa0, bv0, o4);
      o4 = MFMA16(pa1, bv1, o4);
#pragma unroll
      for (int r = 0; r < 4; ++r)
        ob[(row0 + r) * 40 + 16 * dt + L] = (_Float16)o4[r];
    }

    // ---- proj partial: acc_out += O_h @ W2[:,32h:32h+32]^T ----
    f16x8 aa = *(const f16x8*)(ob + (16 * w + L) * 40 + 8 * g);
#pragma unroll
    for (int ct = 0; ct < 12; ++ct) {
      f16x8 w2f = *(const f16x8*)(W2 + (size_t)(16 * ct + L) * DIM + 32 * h + 8 * g);
      acc_out[ct] = MFMA16(aa, w2f, acc_out[ct]);
    }
  }

  // ---- epilogue: out = acc_out + proj_b ----
#pragma unroll
  for (int ct = 0; ct < 12; ++ct) {
    const float pb_ = proj_b[16 * ct + L];
#pragma unroll
    for (int r = 0; r < 4; ++r) {
      int row = row0 + r;
      if (row < NTOK)
        out[((size_t)b * NTOK + row) * DIM + 16 * ct + L] = acc_out[ct][r] + pb_;
    }
  }
}

extern "C" void kernel_launch(void* const* d_in, const int* in_sizes, int n_in,
                              void* d_out, int out_size, void* d_ws, size_t ws_size,
                              hipStream_t stream) {
  const float* x     = (const float*)d_in[0];
  const float* mask  = (const float*)d_in[1];
  const float* qkv_w = (const float*)d_in[2];
  const float* qkv_b = (const float*)d_in[3];
  const float* ls    = (const float*)d_in[4];
  const float* tbl   = (const float*)d_in[5];
  const int*   ridx  = (const int*)d_in[6];
  const float* pw    = (const float*)d_in[7];
  const float* pb    = (const float*)d_in[8];
  float* out = (float*)d_out;
  char* ws = (char*)d_ws;

  _Float16* W1 = (_Float16*)(ws + W1_OFF);
  _Float16* W2 = (_Float16*)(ws + W2_OFF);
  _Float16* bmi = (_Float16*)(ws + BMI_OFF);
  float* hsc = (float*)(ws + HSC_OFF);

  hipLaunchKernelGGL(k_setup, dim3(3602), dim3(256), 0, stream,
                     qkv_w, pw, mask, tbl, ridx, ls, W1, W2, bmi, hsc);
  hipLaunchKernelGGL(k_fused, dim3(BATCH), dim3(256), 0, stream,
                     x, W1, qkv_b, bmi, hsc, W2, pb, out);
}